// Round 1
// baseline (1171.026 us; speedup 1.0000x reference)
//
#include <hip/hip_runtime.h>
#include <hip/hip_bf16.h>
#include <stdint.h>

typedef __attribute__((ext_vector_type(8))) short short8_t;   // 8 x bf16 (4 VGPRs)
typedef __attribute__((ext_vector_type(4))) float f32x4;      // MFMA accum

__device__ __forceinline__ unsigned short f2bf(float f) {
  union { float f; unsigned int u; } a;
  a.f = f;
  unsigned int u = a.u;
  u += 0x7fffu + ((u >> 16) & 1u);   // round-to-nearest-even
  return (unsigned short)(u >> 16);
}

__device__ __forceinline__ void gload_lds16(const void* g, void* l) {
  __builtin_amdgcn_global_load_lds(
      (const __attribute__((address_space(1))) void*)g,
      (__attribute__((address_space(3))) void*)l, 16, 0, 0);
}

// ---------------- LayerNorm: fp32 -> bf16 normed rows ----------------
constexpr int D_IN = 4096;

__global__ __launch_bounds__(256) void ln_bf16_kernel(
    const float* __restrict__ x, const float* __restrict__ lnw,
    const float* __restrict__ lnb, unsigned short* __restrict__ out) {
  const int row = blockIdx.x;
  const int tid = threadIdx.x;
  const float* xr = x + (size_t)row * D_IN;

  float4 v[4];
  float sum = 0.f, sq = 0.f;
#pragma unroll
  for (int i = 0; i < 4; ++i) {
    v[i] = *reinterpret_cast<const float4*>(xr + i * 1024 + tid * 4);
    sum += v[i].x + v[i].y + v[i].z + v[i].w;
    sq += v[i].x * v[i].x + v[i].y * v[i].y + v[i].z * v[i].z + v[i].w * v[i].w;
  }
#pragma unroll
  for (int off = 32; off > 0; off >>= 1) {
    sum += __shfl_down(sum, off, 64);
    sq  += __shfl_down(sq, off, 64);
  }
  __shared__ float s_sum[4], s_sq[4];
  if ((tid & 63) == 0) { s_sum[tid >> 6] = sum; s_sq[tid >> 6] = sq; }
  __syncthreads();
  const float fs = s_sum[0] + s_sum[1] + s_sum[2] + s_sum[3];
  const float fq = s_sq[0] + s_sq[1] + s_sq[2] + s_sq[3];
  const float mean = fs * (1.f / D_IN);
  const float var = fq * (1.f / D_IN) - mean * mean;
  const float rstd = rsqrtf(var + 1e-5f);

  unsigned short* orow = out + (size_t)row * D_IN;
#pragma unroll
  for (int i = 0; i < 4; ++i) {
    const int col = i * 1024 + tid * 4;
    const float4 w = *reinterpret_cast<const float4*>(lnw + col);
    const float4 b = *reinterpret_cast<const float4*>(lnb + col);
    ushort4 o;
    o.x = f2bf((v[i].x - mean) * rstd * w.x + b.x);
    o.y = f2bf((v[i].y - mean) * rstd * w.y + b.y);
    o.z = f2bf((v[i].z - mean) * rstd * w.z + b.z);
    o.w = f2bf((v[i].w - mean) * rstd * w.w + b.w);
    *reinterpret_cast<ushort4*>(orow + col) = o;
  }
}

// ---------------- Weight cast fp32 -> bf16 ----------------
__global__ __launch_bounds__(256) void f32_to_bf16_kernel(
    const float* __restrict__ in, unsigned short* __restrict__ out) {
  const size_t i = ((size_t)blockIdx.x * 256 + threadIdx.x) * 8;
  const float4 a = *reinterpret_cast<const float4*>(in + i);
  const float4 b = *reinterpret_cast<const float4*>(in + i + 4);
  ushort4 lo, hi;
  lo.x = f2bf(a.x); lo.y = f2bf(a.y); lo.z = f2bf(a.z); lo.w = f2bf(a.w);
  hi.x = f2bf(b.x); hi.y = f2bf(b.y); hi.z = f2bf(b.z); hi.w = f2bf(b.w);
  *reinterpret_cast<ushort4*>(out + i) = lo;
  *reinterpret_cast<ushort4*>(out + i + 4) = hi;
}

// ---------------- bf16 GEMM: C = A(MxK) * B(NxK)^T + bias ----------------
// m97 structure: 128x128 tile, BK=32, 4 waves (2x2), each wave 4x4 frags of 16x16x32.
constexpr int BM = 128, BN = 128, BK = 32;

__global__ __launch_bounds__(256) void gemm_bf16_kernel(
    const unsigned short* __restrict__ A,   // M x K bf16 (normed)
    const unsigned short* __restrict__ B,   // N x K bf16 (weight)
    const float* __restrict__ bias,         // N fp32
    float* __restrict__ C,                  // M x N fp32
    int M, int N, int K) {
  __shared__ __align__(16) unsigned short Ash[BM * BK];  // 8 KiB
  __shared__ __align__(16) unsigned short Bsh[BN * BK];  // 8 KiB

  const int tid = threadIdx.x;
  const int lane = tid & 63;
  const int wid = tid >> 6;
  const int m0 = blockIdx.y * BM;
  const int n0 = blockIdx.x * BN;
  const int wrow = (wid >> 1) * 64;
  const int wcol = (wid & 1) * 64;

  f32x4 acc[4][4] = {};

  // staging: linear byte offset b = tid*16 (+4096 for second issue)
  // row = b/64 = tid/4 (+64), k_elem = ((b%64)/2) = (tid&3)*8
  const int srow = tid >> 2;
  const int scol = (tid & 3) * 8;
  const unsigned short* Ag = A + (size_t)(m0 + srow) * K + scol;
  const unsigned short* Bg = B + (size_t)(n0 + srow) * K + scol;
  char* AshB = (char*)Ash + wid * 1024;   // wave-uniform LDS base
  char* BshB = (char*)Bsh + wid * 1024;

  const int kb = (lane >> 4) * 8;   // k offset of fragment
  const int fr = lane & 15;         // row/col within fragment

  for (int k0 = 0; k0 < K; k0 += BK) {
    gload_lds16(Ag + k0,              AshB);
    gload_lds16(Ag + (size_t)64 * K + k0, AshB + 4096);
    gload_lds16(Bg + k0,              BshB);
    gload_lds16(Bg + (size_t)64 * K + k0, BshB + 4096);
    __syncthreads();   // compiler drains vmcnt before barrier

    short8_t af[4], bf[4];
#pragma unroll
    for (int m = 0; m < 4; ++m)
      af[m] = *reinterpret_cast<const short8_t*>(&Ash[(wrow + m * 16 + fr) * BK + kb]);
#pragma unroll
    for (int n = 0; n < 4; ++n)
      bf[n] = *reinterpret_cast<const short8_t*>(&Bsh[(wcol + n * 16 + fr) * BK + kb]);

#pragma unroll
    for (int m = 0; m < 4; ++m)
#pragma unroll
      for (int n = 0; n < 4; ++n)
        acc[m][n] = __builtin_amdgcn_mfma_f32_16x16x32_bf16(af[m], bf[n], acc[m][n], 0, 0, 0);
    __syncthreads();
  }

  // epilogue: C/D layout col = lane&15, row = (lane>>4)*4 + j
  const int fq = lane >> 4;
  float bv[4];
#pragma unroll
  for (int n = 0; n < 4; ++n) bv[n] = bias[n0 + wcol + n * 16 + fr];
#pragma unroll
  for (int m = 0; m < 4; ++m) {
#pragma unroll
    for (int j = 0; j < 4; ++j) {
      const int row = m0 + wrow + m * 16 + fq * 4 + j;
      float* Crow = C + (size_t)row * N + n0 + wcol;
#pragma unroll
      for (int n = 0; n < 4; ++n)
        Crow[n * 16 + fr] = acc[m][n][j] + bv[n];
    }
  }
}

extern "C" void kernel_launch(void* const* d_in, const int* in_sizes, int n_in,
                              void* d_out, int out_size, void* d_ws, size_t ws_size,
                              hipStream_t stream) {
  const float* x    = (const float*)d_in[0];
  const float* w    = (const float*)d_in[1];
  const float* bias = (const float*)d_in[2];
  const float* lnw  = (const float*)d_in[3];
  const float* lnb  = (const float*)d_in[4];
  float* out = (float*)d_out;

  const int DIN  = 4096;
  const int M    = in_sizes[0] / DIN;      // 8192
  const int DOUT = in_sizes[2];            // 12288

  unsigned short* normA = (unsigned short*)d_ws;                 // M x DIN bf16 (64 MiB)
  unsigned short* wB    = normA + (size_t)M * DIN;               // DOUT x DIN bf16 (96 MiB)

  ln_bf16_kernel<<<M, 256, 0, stream>>>(x, lnw, lnb, normA);
  f32_to_bf16_kernel<<<((size_t)DOUT * DIN) / (256 * 8), 256, 0, stream>>>(w, wB);

  dim3 grid(DOUT / BN, M / BM);   // 96 x 64
  gemm_bf16_kernel<<<grid, 256, 0, stream>>>(normA, wB, bias, out, M, DOUT, DIN);
}